// Round 1
// baseline (1555.390 us; speedup 1.0000x reference)
//
#include <hip/hip_runtime.h>
#include <math.h>

static constexpr int BATCH = 4;
static constexpr int SEQ   = 2048;
static constexpr int DIM   = 1024;

// ---------------------------------------------------------------------------
// Fused QKV projection: X[8192,1024] @ {Wq,Wk,Wv}[1024,1024] -> Q,K,V
// 64x64 tile, BK=16, 256 threads, 4x4 per thread per output matrix.
// LDS leading-dim padded to 68 floats: worst aliasing 2-way (free on gfx950).
// ---------------------------------------------------------------------------
__global__ __launch_bounds__(256) void qkv_proj_kernel(
    const float* __restrict__ X, const float* __restrict__ Wq,
    const float* __restrict__ Wk, const float* __restrict__ Wv,
    float* __restrict__ Q, float* __restrict__ K, float* __restrict__ V)
{
    __shared__ float As[16][68];
    __shared__ float Bq[16][68];
    __shared__ float Bk[16][68];
    __shared__ float Bv[16][68];

    const int tid = threadIdx.x;
    const int m0 = blockIdx.y * 64;
    const int n0 = blockIdx.x * 64;

    const int a_row = tid >> 2;        // 0..63
    const int a_k   = (tid & 3) << 2;  // 0,4,8,12
    const int b_k   = tid >> 4;        // 0..15
    const int b_n   = (tid & 15) << 2; // 0..60

    const int ty = tid >> 4;           // 0..15
    const int tx = tid & 15;           // 0..15

    float accQ[4][4] = {{0.f}}, accK[4][4] = {{0.f}}, accV[4][4] = {{0.f}};

    for (int k0 = 0; k0 < DIM; k0 += 16) {
        const float4 av = *(const float4*)(X + (size_t)(m0 + a_row) * DIM + (k0 + a_k));
        As[a_k + 0][a_row] = av.x;
        As[a_k + 1][a_row] = av.y;
        As[a_k + 2][a_row] = av.z;
        As[a_k + 3][a_row] = av.w;
        const size_t boff = (size_t)(k0 + b_k) * DIM + (n0 + b_n);
        *(float4*)&Bq[b_k][b_n] = *(const float4*)(Wq + boff);
        *(float4*)&Bk[b_k][b_n] = *(const float4*)(Wk + boff);
        *(float4*)&Bv[b_k][b_n] = *(const float4*)(Wv + boff);
        __syncthreads();
#pragma unroll
        for (int kk = 0; kk < 16; ++kk) {
            const float4 a4 = *(const float4*)&As[kk][ty * 4];
            const float4 q4 = *(const float4*)&Bq[kk][tx * 4];
            const float4 k4 = *(const float4*)&Bk[kk][tx * 4];
            const float4 v4 = *(const float4*)&Bv[kk][tx * 4];
            const float ar[4] = {a4.x, a4.y, a4.z, a4.w};
            const float qr[4] = {q4.x, q4.y, q4.z, q4.w};
            const float kr[4] = {k4.x, k4.y, k4.z, k4.w};
            const float vr[4] = {v4.x, v4.y, v4.z, v4.w};
#pragma unroll
            for (int i = 0; i < 4; ++i) {
#pragma unroll
                for (int j = 0; j < 4; ++j) {
                    accQ[i][j] = fmaf(ar[i], qr[j], accQ[i][j]);
                    accK[i][j] = fmaf(ar[i], kr[j], accK[i][j]);
                    accV[i][j] = fmaf(ar[i], vr[j], accV[i][j]);
                }
            }
        }
        __syncthreads();
    }
#pragma unroll
    for (int i = 0; i < 4; ++i) {
        const size_t off = (size_t)(m0 + ty * 4 + i) * DIM + (n0 + tx * 4);
        *(float4*)(Q + off) = make_float4(accQ[i][0], accQ[i][1], accQ[i][2], accQ[i][3]);
        *(float4*)(K + off) = make_float4(accK[i][0], accK[i][1], accK[i][2], accK[i][3]);
        *(float4*)(V + off) = make_float4(accV[i][0], accV[i][1], accV[i][2], accV[i][3]);
    }
}

// ---------------------------------------------------------------------------
// Scores: S[b] = Q[b] @ K[b]^T   ([2048,1024] x [2048,1024]^T -> [2048,2048])
// NT GEMM: both operands loaded with the "A-style" transpose-into-LDS pattern.
// ---------------------------------------------------------------------------
__global__ __launch_bounds__(256) void qk_gemm_kernel(
    const float* __restrict__ Q, const float* __restrict__ K,
    float* __restrict__ Sc)
{
    __shared__ float As[16][68];
    __shared__ float Bs[16][68];

    const int tid = threadIdx.x;
    const int b  = blockIdx.z;
    const int m0 = blockIdx.y * 64;
    const int n0 = blockIdx.x * 64;

    const float* __restrict__ Qb = Q + (size_t)b * SEQ * DIM;
    const float* __restrict__ Kb = K + (size_t)b * SEQ * DIM;

    const int a_row = tid >> 2;
    const int a_k   = (tid & 3) << 2;
    const int ty = tid >> 4;
    const int tx = tid & 15;

    float acc[4][4] = {{0.f}};

    for (int k0 = 0; k0 < DIM; k0 += 16) {
        const float4 av = *(const float4*)(Qb + (size_t)(m0 + a_row) * DIM + (k0 + a_k));
        As[a_k + 0][a_row] = av.x;
        As[a_k + 1][a_row] = av.y;
        As[a_k + 2][a_row] = av.z;
        As[a_k + 3][a_row] = av.w;
        const float4 bv = *(const float4*)(Kb + (size_t)(n0 + a_row) * DIM + (k0 + a_k));
        Bs[a_k + 0][a_row] = bv.x;
        Bs[a_k + 1][a_row] = bv.y;
        Bs[a_k + 2][a_row] = bv.z;
        Bs[a_k + 3][a_row] = bv.w;
        __syncthreads();
#pragma unroll
        for (int kk = 0; kk < 16; ++kk) {
            const float4 a4 = *(const float4*)&As[kk][ty * 4];
            const float4 b4 = *(const float4*)&Bs[kk][tx * 4];
            const float ar[4] = {a4.x, a4.y, a4.z, a4.w};
            const float br[4] = {b4.x, b4.y, b4.z, b4.w};
#pragma unroll
            for (int i = 0; i < 4; ++i)
#pragma unroll
                for (int j = 0; j < 4; ++j)
                    acc[i][j] = fmaf(ar[i], br[j], acc[i][j]);
        }
        __syncthreads();
    }
    float* __restrict__ Sb = Sc + (size_t)b * SEQ * SEQ;
#pragma unroll
    for (int i = 0; i < 4; ++i) {
        const size_t off = (size_t)(m0 + ty * 4 + i) * SEQ + (n0 + tx * 4);
        *(float4*)(Sb + off) = make_float4(acc[i][0], acc[i][1], acc[i][2], acc[i][3]);
    }
}

// ---------------------------------------------------------------------------
// Row softmax with mask + 1/sqrt(1024) scale, in place on Sc.
// One 256-thread block per row (8 elements/thread in registers).
// mask[q,k] != 0  =>  -inf before softmax. Mask shared across batch.
// ---------------------------------------------------------------------------
__global__ __launch_bounds__(256) void softmax_kernel(
    float* __restrict__ Sc, const int* __restrict__ mask)
{
    const int r = blockIdx.x;          // 0..8191  (= b*2048 + m)
    const int m = r & (SEQ - 1);
    float* __restrict__ row = Sc + (size_t)r * SEQ;
    const int* __restrict__ mrow = mask + (size_t)m * SEQ;

    const int tid  = threadIdx.x;
    const int lane = tid & 63;
    const int wid  = tid >> 6;

    float x[8];
    float mx = -INFINITY;
#pragma unroll
    for (int j = 0; j < 8; ++j) {
        const int c = tid + j * 256;
        const float s = row[c];
        x[j] = mrow[c] ? -INFINITY : s * 0.03125f;
        mx = fmaxf(mx, x[j]);
    }
    // block max
    __shared__ float redm[4];
#pragma unroll
    for (int off = 32; off > 0; off >>= 1)
        mx = fmaxf(mx, __shfl_down(mx, off, 64));
    if (lane == 0) redm[wid] = mx;
    __syncthreads();
    mx = fmaxf(fmaxf(redm[0], redm[1]), fmaxf(redm[2], redm[3]));

    float sum = 0.f;
#pragma unroll
    for (int j = 0; j < 8; ++j) {
        const float e = __expf(x[j] - mx);
        x[j] = e;
        sum += e;
    }
    __shared__ float reds[4];
#pragma unroll
    for (int off = 32; off > 0; off >>= 1)
        sum += __shfl_down(sum, off, 64);
    if (lane == 0) reds[wid] = sum;
    __syncthreads();
    sum = (reds[0] + reds[1]) + (reds[2] + reds[3]);

    const float inv = 1.0f / sum;
#pragma unroll
    for (int j = 0; j < 8; ++j) {
        const int c = tid + j * 256;
        row[c] = x[j] * inv;
    }
}

// ---------------------------------------------------------------------------
// Output: O[b] = P[b] @ V[b]   ([2048,2048] x [2048,1024] -> [2048,1024])
// ---------------------------------------------------------------------------
__global__ __launch_bounds__(256) void pv_gemm_kernel(
    const float* __restrict__ P, const float* __restrict__ V,
    float* __restrict__ O)
{
    __shared__ float As[16][68];
    __shared__ float Bs[16][68];

    const int tid = threadIdx.x;
    const int b  = blockIdx.z;
    const int m0 = blockIdx.y * 64;
    const int n0 = blockIdx.x * 64;

    const float* __restrict__ Pb = P + (size_t)b * SEQ * SEQ;
    const float* __restrict__ Vb = V + (size_t)b * SEQ * DIM;
    float* __restrict__ Ob       = O + (size_t)b * SEQ * DIM;

    const int a_row = tid >> 2;
    const int a_k   = (tid & 3) << 2;
    const int b_k   = tid >> 4;
    const int b_n   = (tid & 15) << 2;
    const int ty = tid >> 4;
    const int tx = tid & 15;

    float acc[4][4] = {{0.f}};

    for (int k0 = 0; k0 < SEQ; k0 += 16) {
        const float4 av = *(const float4*)(Pb + (size_t)(m0 + a_row) * SEQ + (k0 + a_k));
        As[a_k + 0][a_row] = av.x;
        As[a_k + 1][a_row] = av.y;
        As[a_k + 2][a_row] = av.z;
        As[a_k + 3][a_row] = av.w;
        *(float4*)&Bs[b_k][b_n] = *(const float4*)(Vb + (size_t)(k0 + b_k) * DIM + (n0 + b_n));
        __syncthreads();
#pragma unroll
        for (int kk = 0; kk < 16; ++kk) {
            const float4 a4 = *(const float4*)&As[kk][ty * 4];
            const float4 b4 = *(const float4*)&Bs[kk][tx * 4];
            const float ar[4] = {a4.x, a4.y, a4.z, a4.w};
            const float br[4] = {b4.x, b4.y, b4.z, b4.w};
#pragma unroll
            for (int i = 0; i < 4; ++i)
#pragma unroll
                for (int j = 0; j < 4; ++j)
                    acc[i][j] = fmaf(ar[i], br[j], acc[i][j]);
        }
        __syncthreads();
    }
#pragma unroll
    for (int i = 0; i < 4; ++i) {
        const size_t off = (size_t)(m0 + ty * 4 + i) * DIM + (n0 + tx * 4);
        *(float4*)(Ob + off) = make_float4(acc[i][0], acc[i][1], acc[i][2], acc[i][3]);
    }
}

// ---------------------------------------------------------------------------
// Workspace layout (bytes):
//   Q: [8192,1024] f32   33 554 432
//   K: [8192,1024] f32   33 554 432
//   V: [8192,1024] f32   33 554 432
//   S: [4,2048,2048] f32 67 108 864
// total: 167 772 160
// ---------------------------------------------------------------------------
extern "C" void kernel_launch(void* const* d_in, const int* in_sizes, int n_in,
                              void* d_out, int out_size, void* d_ws, size_t ws_size,
                              hipStream_t stream)
{
    const float* x    = (const float*)d_in[0];
    const int*   mask = (const int*)d_in[1];
    const float* wq   = (const float*)d_in[2];
    const float* wk   = (const float*)d_in[3];
    const float* wv   = (const float*)d_in[4];
    float* out = (float*)d_out;

    float* Q  = (float*)d_ws;
    float* K  = Q + (size_t)BATCH * SEQ * DIM;
    float* V  = K + (size_t)BATCH * SEQ * DIM;
    float* Sc = V + (size_t)BATCH * SEQ * DIM;

    // QKV projections: M=8192, N=1024 in 64x64 tiles
    qkv_proj_kernel<<<dim3(DIM / 64, (BATCH * SEQ) / 64), 256, 0, stream>>>(
        x, wq, wk, wv, Q, K, V);

    // Scores: per batch 2048x2048 in 64x64 tiles
    qk_gemm_kernel<<<dim3(SEQ / 64, SEQ / 64, BATCH), 256, 0, stream>>>(Q, K, Sc);

    // Masked scaled softmax, one block per row
    softmax_kernel<<<dim3(BATCH * SEQ), 256, 0, stream>>>(Sc, mask);

    // O = P @ V: per batch 2048x1024 in 64x64 tiles
    pv_gemm_kernel<<<dim3(DIM / 64, SEQ / 64, BATCH), 256, 0, stream>>>(Sc, V, out);
}

// Round 2
// 478.504 us; speedup vs baseline: 3.2505x; 3.2505x over previous
//
#include <hip/hip_runtime.h>
#include <math.h>

static constexpr int BATCH = 4;
static constexpr int SEQ   = 2048;
static constexpr int DIM   = 1024;

typedef __attribute__((ext_vector_type(8))) short     bf16x8;  // MFMA A/B frag (4 VGPRs)
typedef __attribute__((ext_vector_type(4))) float     f32x4;   // MFMA C/D frag
typedef __attribute__((ext_vector_type(8))) unsigned short u16x8; // 16B staging vector

// fp32 -> bf16 (RNE) and back, bit-exact helpers for hi/lo splitting
__device__ __forceinline__ unsigned short f2b(float v) {
    unsigned int u = __float_as_uint(v);
    u = u + 0x7fffu + ((u >> 16) & 1u);
    return (unsigned short)(u >> 16);
}
__device__ __forceinline__ float b2f(unsigned short h) {
    return __uint_as_float(((unsigned int)h) << 16);
}

// ---------------------------------------------------------------------------
// convert_x: fp32 -> (hi, lo) bf16, elementwise. X is 8.39M floats.
// ---------------------------------------------------------------------------
__global__ __launch_bounds__(256) void convert_x_kernel(
    const float* __restrict__ X, unsigned short* __restrict__ hi,
    unsigned short* __restrict__ lo)
{
    const int i = blockIdx.x * 256 + threadIdx.x;   // float4 index
    const float4 v = ((const float4*)X)[i];
    ushort4 h, l;
    h.x = f2b(v.x); l.x = f2b(v.x - b2f(h.x));
    h.y = f2b(v.y); l.y = f2b(v.y - b2f(h.y));
    h.z = f2b(v.z); l.z = f2b(v.z - b2f(h.z));
    h.w = f2b(v.w); l.w = f2b(v.w - b2f(h.w));
    ((ushort4*)hi)[i] = h;
    ((ushort4*)lo)[i] = l;
}

// ---------------------------------------------------------------------------
// convert_w: W[k][n] fp32 -> WT[n][k] (hi, lo) bf16. 32x32 LDS tile transpose.
// blockIdx.z picks Wq/Wk/Wv; outputs at z*1024*1024.
// ---------------------------------------------------------------------------
__global__ __launch_bounds__(256) void convert_w_kernel(
    const float* __restrict__ W0, const float* __restrict__ W1,
    const float* __restrict__ W2,
    unsigned short* __restrict__ WThi, unsigned short* __restrict__ WTlo)
{
    __shared__ float t[32][33];
    const int z = blockIdx.z;
    const float* __restrict__ W = (z == 0) ? W0 : (z == 1) ? W1 : W2;
    unsigned short* __restrict__ hi = WThi + (size_t)z * DIM * DIM;
    unsigned short* __restrict__ lo = WTlo + (size_t)z * DIM * DIM;
    const int n0 = blockIdx.x * 32, k0 = blockIdx.y * 32;
    const int tx = threadIdx.x & 31, ty = threadIdx.x >> 5;  // ty: 0..7
#pragma unroll
    for (int i = 0; i < 4; ++i)
        t[ty + i * 8][tx] = W[(size_t)(k0 + ty + i * 8) * DIM + (n0 + tx)];
    __syncthreads();
#pragma unroll
    for (int i = 0; i < 4; ++i) {
        const float v = t[tx][ty + i * 8];         // = W[k0+tx][n0+ty+i*8]
        const unsigned short h = f2b(v);
        const size_t off = (size_t)(n0 + ty + i * 8) * DIM + (k0 + tx);
        hi[off] = h;
        lo[off] = f2b(v - b2f(h));
    }
}

// ---------------------------------------------------------------------------
// transpose_v: V[b][s][d] bf16 -> Vt[b][d][s] bf16 (for PV B-operand).
// ---------------------------------------------------------------------------
__global__ __launch_bounds__(256) void transpose_v_kernel(
    const unsigned short* __restrict__ V, unsigned short* __restrict__ Vt)
{
    __shared__ unsigned short t[32][33];
    const int b = blockIdx.z;
    const unsigned short* __restrict__ Vb = V + (size_t)b * SEQ * DIM;
    unsigned short* __restrict__ Vtb      = Vt + (size_t)b * DIM * SEQ;
    const int d0 = blockIdx.x * 32, s0 = blockIdx.y * 32;
    const int tx = threadIdx.x & 31, ty = threadIdx.x >> 5;
#pragma unroll
    for (int i = 0; i < 4; ++i)
        t[ty + i * 8][tx] = Vb[(size_t)(s0 + ty + i * 8) * DIM + (d0 + tx)];
    __syncthreads();
#pragma unroll
    for (int i = 0; i < 4; ++i)
        Vtb[(size_t)(d0 + ty + i * 8) * SEQ + (s0 + tx)] = t[tx][ty + i * 8];
}

// ---------------------------------------------------------------------------
// LDS staging: 128 rows x 32 bf16, rows padded to 40 (2-way bank alias = free).
// Each of 256 threads stages two 16B chunks.
// ---------------------------------------------------------------------------
static constexpr int LDSW = 40;

__device__ __forceinline__ void stage_tile(
    const unsigned short* __restrict__ g, size_t gstride, int row0, int k0,
    unsigned short* lds, int tid)
{
#pragma unroll
    for (int h = 0; h < 2; ++h) {
        const int s = tid + h * 256;
        const int row = s >> 2, chunk = s & 3;
        const unsigned short* src = g + (size_t)(row0 + row) * gstride + k0 + chunk * 8;
        *(u16x8*)(lds + row * LDSW + chunk * 8) = *(const u16x8*)src;
    }
}

__device__ __forceinline__ bf16x8 frag(const unsigned short* lds, int outer, int quad)
{
    return *(const bf16x8*)(lds + outer * LDSW + quad * 8);
}

// ---------------------------------------------------------------------------
// Split-bf16 NT GEMM core, 128x128 tile, 4 waves (64x64 each), K-step 32.
// acc += Ahi*Bhi + Ahi*Blo + Alo*Bhi  (fp32 MFMA accumulation).
// ---------------------------------------------------------------------------

// QKV projection: A = X (hi/lo) [8192][1024]; B = WT (hi/lo) [1024][1024],
// z picks the matrix. Writes C as hi/lo bf16 (lo skipped for V).
__global__ __launch_bounds__(256) void proj_mfma_kernel(
    const unsigned short* __restrict__ Xhi, const unsigned short* __restrict__ Xlo,
    const unsigned short* __restrict__ WThi, const unsigned short* __restrict__ WTlo,
    unsigned short* __restrict__ Qhi, unsigned short* __restrict__ Qlo,
    unsigned short* __restrict__ Khi, unsigned short* __restrict__ Klo,
    unsigned short* __restrict__ Vhi)
{
    __shared__ unsigned short Ah[128 * LDSW], Al[128 * LDSW];
    __shared__ unsigned short Bh[128 * LDSW], Bl[128 * LDSW];

    const int tid = threadIdx.x;
    const int w = tid >> 6, lane = tid & 63;
    const int wm = (w >> 1) * 64, wn = (w & 1) * 64;
    const int m0 = blockIdx.y * 128, n0 = blockIdx.x * 128;
    const int z = blockIdx.z;

    const unsigned short* __restrict__ Bhg = WThi + (size_t)z * DIM * DIM;
    const unsigned short* __restrict__ Blg = WTlo + (size_t)z * DIM * DIM;
    unsigned short* __restrict__ Chi = (z == 0) ? Qhi : (z == 1) ? Khi : Vhi;
    unsigned short* __restrict__ Clo = (z == 0) ? Qlo : (z == 1) ? Klo : nullptr;

    f32x4 acc[4][4];
#pragma unroll
    for (int i = 0; i < 4; ++i)
#pragma unroll
        for (int j = 0; j < 4; ++j) acc[i][j] = (f32x4){0.f, 0.f, 0.f, 0.f};

    const int quad = lane >> 4, fr = lane & 15;

    for (int k0 = 0; k0 < DIM; k0 += 32) {
        stage_tile(Xhi, DIM, m0, k0, Ah, tid);
        stage_tile(Xlo, DIM, m0, k0, Al, tid);
        stage_tile(Bhg, DIM, n0, k0, Bh, tid);
        stage_tile(Blg, DIM, n0, k0, Bl, tid);
        __syncthreads();

        bf16x8 ah[4], al[4];
#pragma unroll
        for (int mt = 0; mt < 4; ++mt) {
            ah[mt] = frag(Ah, wm + mt * 16 + fr, quad);
            al[mt] = frag(Al, wm + mt * 16 + fr, quad);
        }
#pragma unroll
        for (int nt = 0; nt < 4; ++nt) {
            const bf16x8 bh = frag(Bh, wn + nt * 16 + fr, quad);
            const bf16x8 bl = frag(Bl, wn + nt * 16 + fr, quad);
#pragma unroll
            for (int mt = 0; mt < 4; ++mt) {
                acc[mt][nt] = __builtin_amdgcn_mfma_f32_16x16x32_bf16(ah[mt], bh, acc[mt][nt], 0, 0, 0);
                acc[mt][nt] = __builtin_amdgcn_mfma_f32_16x16x32_bf16(ah[mt], bl, acc[mt][nt], 0, 0, 0);
                acc[mt][nt] = __builtin_amdgcn_mfma_f32_16x16x32_bf16(al[mt], bh, acc[mt][nt], 0, 0, 0);
            }
        }
        __syncthreads();
    }

    const int col = lane & 15, rq = lane >> 4;
#pragma unroll
    for (int mt = 0; mt < 4; ++mt)
#pragma unroll
        for (int nt = 0; nt < 4; ++nt)
#pragma unroll
            for (int e = 0; e < 4; ++e) {
                const int m = m0 + wm + mt * 16 + rq * 4 + e;
                const int n = n0 + wn + nt * 16 + col;
                const float v = acc[mt][nt][e];
                const unsigned short h = f2b(v);
                Chi[(size_t)m * DIM + n] = h;
                if (Clo) Clo[(size_t)m * DIM + n] = f2b(v - b2f(h));
            }
}

// Scores: S[b] = Q[b] . K[b]^T, split-bf16, fp32 output (unscaled, unmasked).
__global__ __launch_bounds__(256) void qk_mfma_kernel(
    const unsigned short* __restrict__ Qhi, const unsigned short* __restrict__ Qlo,
    const unsigned short* __restrict__ Khi, const unsigned short* __restrict__ Klo,
    float* __restrict__ Sc)
{
    __shared__ unsigned short Ah[128 * LDSW], Al[128 * LDSW];
    __shared__ unsigned short Bh[128 * LDSW], Bl[128 * LDSW];

    const int tid = threadIdx.x;
    const int w = tid >> 6, lane = tid & 63;
    const int wm = (w >> 1) * 64, wn = (w & 1) * 64;
    const int m0 = blockIdx.y * 128, n0 = blockIdx.x * 128;
    const int b = blockIdx.z;

    const unsigned short* __restrict__ Ahg = Qhi + (size_t)b * SEQ * DIM;
    const unsigned short* __restrict__ Alg = Qlo + (size_t)b * SEQ * DIM;
    const unsigned short* __restrict__ Bhg = Khi + (size_t)b * SEQ * DIM;
    const unsigned short* __restrict__ Blg = Klo + (size_t)b * SEQ * DIM;
    float* __restrict__ Sb = Sc + (size_t)b * SEQ * SEQ;

    f32x4 acc[4][4];
#pragma unroll
    for (int i = 0; i < 4; ++i)
#pragma unroll
        for (int j = 0; j < 4; ++j) acc[i][j] = (f32x4){0.f, 0.f, 0.f, 0.f};

    const int quad = lane >> 4, fr = lane & 15;

    for (int k0 = 0; k0 < DIM; k0 += 32) {
        stage_tile(Ahg, DIM, m0, k0, Ah, tid);
        stage_tile(Alg, DIM, m0, k0, Al, tid);
        stage_tile(Bhg, DIM, n0, k0, Bh, tid);
        stage_tile(Blg, DIM, n0, k0, Bl, tid);
        __syncthreads();

        bf16x8 ah[4], al[4];
#pragma unroll
        for (int mt = 0; mt < 4; ++mt) {
            ah[mt] = frag(Ah, wm + mt * 16 + fr, quad);
            al[mt] = frag(Al, wm + mt * 16 + fr, quad);
        }
#pragma unroll
        for (int nt = 0; nt < 4; ++nt) {
            const bf16x8 bh = frag(Bh, wn + nt * 16 + fr, quad);
            const bf16x8 bl = frag(Bl, wn + nt * 16 + fr, quad);
#pragma unroll
            for (int mt = 0; mt < 4; ++mt) {
                acc[mt][nt] = __builtin_amdgcn_mfma_f32_16x16x32_bf16(ah[mt], bh, acc[mt][nt], 0, 0, 0);
                acc[mt][nt] = __builtin_amdgcn_mfma_f32_16x16x32_bf16(ah[mt], bl, acc[mt][nt], 0, 0, 0);
                acc[mt][nt] = __builtin_amdgcn_mfma_f32_16x16x32_bf16(al[mt], bh, acc[mt][nt], 0, 0, 0);
            }
        }
        __syncthreads();
    }

    const int col = lane & 15, rq = lane >> 4;
#pragma unroll
    for (int mt = 0; mt < 4; ++mt)
#pragma unroll
        for (int nt = 0; nt < 4; ++nt)
#pragma unroll
            for (int e = 0; e < 4; ++e) {
                const int m = m0 + wm + mt * 16 + rq * 4 + e;
                const int n = n0 + wn + nt * 16 + col;
                Sb[(size_t)m * SEQ + n] = acc[mt][nt][e];
            }
}

// ---------------------------------------------------------------------------
// Row softmax (mask + 1/32 scale), reads fp32 S row, writes bf16 P in place
// at the start of the same row (P row r = (ushort*)S + r*4096, first 2048).
// ---------------------------------------------------------------------------
__global__ __launch_bounds__(256) void softmax_kernel(
    float* __restrict__ Sc, const int* __restrict__ mask)
{
    const int r = blockIdx.x;          // b*2048 + m
    const int m = r & (SEQ - 1);
    float* __restrict__ row = Sc + (size_t)r * SEQ;
    const int* __restrict__ mrow = mask + (size_t)m * SEQ;

    const int tid  = threadIdx.x;
    const int lane = tid & 63;
    const int wid  = tid >> 6;

    float x[8];
    float mx = -INFINITY;
#pragma unroll
    for (int j = 0; j < 8; ++j) {
        const int c = tid + j * 256;
        const float s = row[c];
        x[j] = mrow[c] ? -INFINITY : s * 0.03125f;
        mx = fmaxf(mx, x[j]);
    }
    __shared__ float redm[4];
#pragma unroll
    for (int off = 32; off > 0; off >>= 1)
        mx = fmaxf(mx, __shfl_down(mx, off, 64));
    if (lane == 0) redm[wid] = mx;
    __syncthreads();
    mx = fmaxf(fmaxf(redm[0], redm[1]), fmaxf(redm[2], redm[3]));

    float sum = 0.f;
#pragma unroll
    for (int j = 0; j < 8; ++j) {
        const float e = __expf(x[j] - mx);
        x[j] = e;
        sum += e;
    }
    __shared__ float reds[4];
#pragma unroll
    for (int off = 32; off > 0; off >>= 1)
        sum += __shfl_down(sum, off, 64);
    if (lane == 0) reds[wid] = sum;
    __syncthreads();
    sum = (reds[0] + reds[1]) + (reds[2] + reds[3]);

    const float inv = 1.0f / sum;
    unsigned short* __restrict__ prow = (unsigned short*)row;
#pragma unroll
    for (int j = 0; j < 8; ++j) {
        const int c = tid + j * 256;
        prow[c] = f2b(x[j] * inv);
    }
}

// ---------------------------------------------------------------------------
// O[b] = P[b] @ V[b]: single bf16 MFMA. A = P rows (stride 4096 ushorts),
// B = Vt [1024][2048] rows (n-major, k contiguous). fp32 output.
// ---------------------------------------------------------------------------
__global__ __launch_bounds__(256) void pv_mfma_kernel(
    const unsigned short* __restrict__ P, const unsigned short* __restrict__ Vt,
    float* __restrict__ O)
{
    __shared__ unsigned short As[128 * LDSW], Bs[128 * LDSW];

    const int tid = threadIdx.x;
    const int w = tid >> 6, lane = tid & 63;
    const int wm = (w >> 1) * 64, wn = (w & 1) * 64;
    const int m0 = blockIdx.y * 128, n0 = blockIdx.x * 128;
    const int b = blockIdx.z;

    const unsigned short* __restrict__ Ag = P + (size_t)b * SEQ * (2 * SEQ);
    const unsigned short* __restrict__ Bg = Vt + (size_t)b * DIM * SEQ;
    float* __restrict__ Ob = O + (size_t)b * SEQ * DIM;

    f32x4 acc[4][4];
#pragma unroll
    for (int i = 0; i < 4; ++i)
#pragma unroll
        for (int j = 0; j < 4; ++j) acc[i][j] = (f32x4){0.f, 0.f, 0.f, 0.f};

    const int quad = lane >> 4, fr = lane & 15;

    for (int k0 = 0; k0 < SEQ; k0 += 32) {
        stage_tile(Ag, 2 * SEQ, m0, k0, As, tid);   // P rows have stride 4096
        stage_tile(Bg, SEQ,     n0, k0, Bs, tid);
        __syncthreads();

        bf16x8 af[4];
#pragma unroll
        for (int mt = 0; mt < 4; ++mt)
            af[mt] = frag(As, wm + mt * 16 + fr, quad);
#pragma unroll
        for (int nt = 0; nt < 4; ++nt) {
            const bf16x8 bf = frag(Bs, wn + nt * 16 + fr, quad);
#pragma unroll
            for (int mt = 0; mt < 4; ++mt)
                acc[mt][nt] = __builtin_amdgcn_mfma_f32_16x16x32_bf16(af[mt], bf, acc[mt][nt], 0, 0, 0);
        }
        __syncthreads();
    }

    const int col = lane & 15, rq = lane >> 4;
#pragma unroll
    for (int mt = 0; mt < 4; ++mt)
#pragma unroll
        for (int nt = 0; nt < 4; ++nt)
#pragma unroll
            for (int e = 0; e < 4; ++e) {
                const int m = m0 + wm + mt * 16 + rq * 4 + e;
                const int n = n0 + wn + nt * 16 + col;
                Ob[(size_t)m * DIM + n] = acc[mt][nt][e];
            }
}

// ---------------------------------------------------------------------------
// Workspace layout (bytes), total = 167 772 160:
//   Qhi/Qlo/Khi/Klo/Vhi/Vt : 6 x 16 777 216  (bf16 [8192][1024] each)
//   S                      : 67 108 864      (fp32 [4][2048][2048])
// Transient, aliased INSIDE the S region (consumed before S is written):
//   Xhi/Xlo (33.5 MB) + WThi/WTlo (12.6 MB)
// P (bf16) is written in place into S rows (row r at ushort offset r*4096).
// ---------------------------------------------------------------------------
extern "C" void kernel_launch(void* const* d_in, const int* in_sizes, int n_in,
                              void* d_out, int out_size, void* d_ws, size_t ws_size,
                              hipStream_t stream)
{
    const float* x    = (const float*)d_in[0];
    const int*   mask = (const int*)d_in[1];
    const float* wq   = (const float*)d_in[2];
    const float* wk   = (const float*)d_in[3];
    const float* wv   = (const float*)d_in[4];
    float* out = (float*)d_out;

    const size_t NQ = (size_t)BATCH * SEQ * DIM;     // 8 388 608
    unsigned short* Qhi = (unsigned short*)d_ws;
    unsigned short* Qlo = Qhi + NQ;
    unsigned short* Khi = Qlo + NQ;
    unsigned short* Klo = Khi + NQ;
    unsigned short* Vhi = Klo + NQ;
    unsigned short* Vt  = Vhi + NQ;
    float* Sc = (float*)(Vt + NQ);

    unsigned short* Xhi  = (unsigned short*)Sc;      // transient aliases
    unsigned short* Xlo  = Xhi + NQ;
    unsigned short* WThi = Xlo + NQ;
    unsigned short* WTlo = WThi + (size_t)3 * DIM * DIM;

    // 1. X -> hi/lo bf16
    convert_x_kernel<<<dim3(NQ / 4 / 256), 256, 0, stream>>>(x, Xhi, Xlo);
    // 2. W -> WT hi/lo bf16 (transposed to [n][k])
    convert_w_kernel<<<dim3(32, 32, 3), 256, 0, stream>>>(wq, wk, wv, WThi, WTlo);
    // 3. QKV projections (split-bf16 MFMA); z = 0/1/2 -> Q/K/V
    proj_mfma_kernel<<<dim3(DIM / 128, BATCH * SEQ / 128, 3), 256, 0, stream>>>(
        Xhi, Xlo, WThi, WTlo, Qhi, Qlo, Khi, Klo, Vhi);
    // 4. V -> Vt (per batch [d][s])
    transpose_v_kernel<<<dim3(DIM / 32, SEQ / 32, BATCH), 256, 0, stream>>>(Vhi, Vt);
    // 5. S = Q.K^T (split-bf16 MFMA, fp32 scores)
    qk_mfma_kernel<<<dim3(SEQ / 128, SEQ / 128, BATCH), 256, 0, stream>>>(
        Qhi, Qlo, Khi, Klo, Sc);
    // 6. masked scaled softmax; writes bf16 P in place
    softmax_kernel<<<dim3(BATCH * SEQ), 256, 0, stream>>>(Sc, mask);
    // 7. O = P @ V
    pv_mfma_kernel<<<dim3(DIM / 128, SEQ / 128, BATCH), 256, 0, stream>>>(
        (const unsigned short*)Sc, Vt, out);
}

// Round 3
// 434.712 us; speedup vs baseline: 3.5780x; 1.1007x over previous
//
#include <hip/hip_runtime.h>
#include <math.h>

static constexpr int BATCH = 4;
static constexpr int SEQ   = 2048;
static constexpr int DIM   = 1024;

typedef __attribute__((ext_vector_type(8))) short     bf16x8;  // MFMA A/B frag (4 VGPRs)
typedef __attribute__((ext_vector_type(4))) float     f32x4;   // MFMA C/D frag

// fp32 -> bf16 (RNE) and back, bit-exact helpers for hi/lo splitting
__device__ __forceinline__ unsigned short f2b(float v) {
    unsigned int u = __float_as_uint(v);
    u = u + 0x7fffu + ((u >> 16) & 1u);
    return (unsigned short)(u >> 16);
}
__device__ __forceinline__ float b2f(unsigned short h) {
    return __uint_as_float(((unsigned int)h) << 16);
}

// ---------------------------------------------------------------------------
// convert_x: fp32 -> (hi, lo) bf16, elementwise.
// ---------------------------------------------------------------------------
__global__ __launch_bounds__(256) void convert_x_kernel(
    const float* __restrict__ X, unsigned short* __restrict__ hi,
    unsigned short* __restrict__ lo)
{
    const int i = blockIdx.x * 256 + threadIdx.x;   // float4 index
    const float4 v = ((const float4*)X)[i];
    ushort4 h, l;
    h.x = f2b(v.x); l.x = f2b(v.x - b2f(h.x));
    h.y = f2b(v.y); l.y = f2b(v.y - b2f(h.y));
    h.z = f2b(v.z); l.z = f2b(v.z - b2f(h.z));
    h.w = f2b(v.w); l.w = f2b(v.w - b2f(h.w));
    ((ushort4*)hi)[i] = h;
    ((ushort4*)lo)[i] = l;
}

// ---------------------------------------------------------------------------
// convert_w: W[k][n] fp32 -> WT[n][k] (hi, lo) bf16. 32x32 LDS tile transpose.
// ---------------------------------------------------------------------------
__global__ __launch_bounds__(256) void convert_w_kernel(
    const float* __restrict__ W0, const float* __restrict__ W1,
    const float* __restrict__ W2,
    unsigned short* __restrict__ WThi, unsigned short* __restrict__ WTlo)
{
    __shared__ float t[32][33];
    const int z = blockIdx.z;
    const float* __restrict__ W = (z == 0) ? W0 : (z == 1) ? W1 : W2;
    unsigned short* __restrict__ hi = WThi + (size_t)z * DIM * DIM;
    unsigned short* __restrict__ lo = WTlo + (size_t)z * DIM * DIM;
    const int n0 = blockIdx.x * 32, k0 = blockIdx.y * 32;
    const int tx = threadIdx.x & 31, ty = threadIdx.x >> 5;  // ty: 0..7
#pragma unroll
    for (int i = 0; i < 4; ++i)
        t[ty + i * 8][tx] = W[(size_t)(k0 + ty + i * 8) * DIM + (n0 + tx)];
    __syncthreads();
#pragma unroll
    for (int i = 0; i < 4; ++i) {
        const float v = t[tx][ty + i * 8];         // = W[k0+tx][n0+ty+i*8]
        const unsigned short h = f2b(v);
        const size_t off = (size_t)(n0 + ty + i * 8) * DIM + (k0 + tx);
        hi[off] = h;
        lo[off] = f2b(v - b2f(h));
    }
}

// ---------------------------------------------------------------------------
// transpose_v: V[b][s][d] bf16 -> Vt[b][d][s] bf16 (PV B-operand).
// ---------------------------------------------------------------------------
__global__ __launch_bounds__(256) void transpose_v_kernel(
    const unsigned short* __restrict__ V, unsigned short* __restrict__ Vt)
{
    __shared__ unsigned short t[32][33];
    const int b = blockIdx.z;
    const unsigned short* __restrict__ Vb = V + (size_t)b * SEQ * DIM;
    unsigned short* __restrict__ Vtb      = Vt + (size_t)b * DIM * SEQ;
    const int d0 = blockIdx.x * 32, s0 = blockIdx.y * 32;
    const int tx = threadIdx.x & 31, ty = threadIdx.x >> 5;
#pragma unroll
    for (int i = 0; i < 4; ++i)
        t[ty + i * 8][tx] = Vb[(size_t)(s0 + ty + i * 8) * DIM + (d0 + tx)];
    __syncthreads();
#pragma unroll
    for (int i = 0; i < 4; ++i)
        Vtb[(size_t)(d0 + ty + i * 8) * SEQ + (s0 + tx)] = t[tx][ty + i * 8];
}

// ---------------------------------------------------------------------------
// Async staging of one 128-row x 32-elem bf16 tile via global_load_lds w=16.
// LDS layout: unpadded 64 B rows, chunk slot s of row r holds global 16 B
// chunk  s ^ ((r>>2)&3)  (XOR swizzle -> uniform 2-way banks on frag reads,
// and the LDS destination is exactly wave-uniform-base + lane*16).
// Wave w stages rows [32w, 32w+32) with two 1024 B instructions.
// ---------------------------------------------------------------------------
__device__ __forceinline__ void stage_async(
    const unsigned short* __restrict__ g, int gstride, int row0, int k0,
    unsigned short* lds, int tid)
{
    const int w = tid >> 6, lane = tid & 63;
    const int c = (lane & 3) ^ ((lane >> 4) & 3);   // global chunk this lane fetches
#pragma unroll
    for (int h = 0; h < 2; ++h) {
        const int row = 32 * w + 16 * h + (lane >> 2);
        const unsigned short* src = g + (size_t)(row0 + row) * gstride + k0 + 8 * c;
        unsigned short* dst = lds + (32 * w + 16 * h) * 32;   // wave-uniform
        __builtin_amdgcn_global_load_lds(
            (const __attribute__((address_space(1))) void*)src,
            (__attribute__((address_space(3))) void*)dst, 16, 0, 0);
    }
}

// frag read: row = tile row, qsw = quad ^ ((fr>>2)&3) precomputed per lane
__device__ __forceinline__ bf16x8 fragr(const unsigned short* lds, int row, int qsw)
{
    return *(const bf16x8*)(lds + row * 32 + qsw * 8);
}

// ---------------------------------------------------------------------------
// QKV projection, split-bf16 MFMA (Q,K: 3 terms; V: 1 term), 128x128 tile.
// ---------------------------------------------------------------------------
__global__ __launch_bounds__(256) void proj_mfma_kernel(
    const unsigned short* __restrict__ Xhi, const unsigned short* __restrict__ Xlo,
    const unsigned short* __restrict__ WThi, const unsigned short* __restrict__ WTlo,
    unsigned short* __restrict__ Qhi, unsigned short* __restrict__ Qlo,
    unsigned short* __restrict__ Khi, unsigned short* __restrict__ Klo,
    unsigned short* __restrict__ Vhi)
{
    __shared__ unsigned short Ah[128 * 32], Al[128 * 32];
    __shared__ unsigned short Bh[128 * 32], Bl[128 * 32];

    const int tid = threadIdx.x;
    const int w = tid >> 6, lane = tid & 63;
    const int wm = (w >> 1) * 64, wn = (w & 1) * 64;
    const int m0 = blockIdx.y * 128, n0 = blockIdx.x * 128;
    const int z = blockIdx.z;
    const bool full = (z < 2);          // V (z==2): single hi*hi term

    const unsigned short* __restrict__ Bhg = WThi + (size_t)z * DIM * DIM;
    const unsigned short* __restrict__ Blg = WTlo + (size_t)z * DIM * DIM;
    unsigned short* __restrict__ Chi = (z == 0) ? Qhi : (z == 1) ? Khi : Vhi;
    unsigned short* __restrict__ Clo = (z == 0) ? Qlo : (z == 1) ? Klo : nullptr;

    f32x4 acc[4][4];
#pragma unroll
    for (int i = 0; i < 4; ++i)
#pragma unroll
        for (int j = 0; j < 4; ++j) acc[i][j] = (f32x4){0.f, 0.f, 0.f, 0.f};

    const int fr = lane & 15, quad = lane >> 4;
    const int qsw = quad ^ ((fr >> 2) & 3);

    for (int k0 = 0; k0 < DIM; k0 += 32) {
        stage_async(Xhi, DIM, m0, k0, Ah, tid);
        stage_async(Bhg, DIM, n0, k0, Bh, tid);
        if (full) {
            stage_async(Xlo, DIM, m0, k0, Al, tid);
            stage_async(Blg, DIM, n0, k0, Bl, tid);
        }
        __syncthreads();

        bf16x8 ah[4], al[4];
#pragma unroll
        for (int mt = 0; mt < 4; ++mt)
            ah[mt] = fragr(Ah, wm + mt * 16 + fr, qsw);
        if (full) {
#pragma unroll
            for (int mt = 0; mt < 4; ++mt)
                al[mt] = fragr(Al, wm + mt * 16 + fr, qsw);
        }
#pragma unroll
        for (int nt = 0; nt < 4; ++nt) {
            const bf16x8 bh = fragr(Bh, wn + nt * 16 + fr, qsw);
#pragma unroll
            for (int mt = 0; mt < 4; ++mt)
                acc[mt][nt] = __builtin_amdgcn_mfma_f32_16x16x32_bf16(ah[mt], bh, acc[mt][nt], 0, 0, 0);
            if (full) {
                const bf16x8 bl = fragr(Bl, wn + nt * 16 + fr, qsw);
#pragma unroll
                for (int mt = 0; mt < 4; ++mt) {
                    acc[mt][nt] = __builtin_amdgcn_mfma_f32_16x16x32_bf16(ah[mt], bl, acc[mt][nt], 0, 0, 0);
                    acc[mt][nt] = __builtin_amdgcn_mfma_f32_16x16x32_bf16(al[mt], bh, acc[mt][nt], 0, 0, 0);
                }
            }
        }
        __syncthreads();
    }

    const int col = lane & 15, rq = lane >> 4;
#pragma unroll
    for (int mt = 0; mt < 4; ++mt)
#pragma unroll
        for (int nt = 0; nt < 4; ++nt)
#pragma unroll
            for (int e = 0; e < 4; ++e) {
                const int m = m0 + wm + mt * 16 + rq * 4 + e;
                const int n = n0 + wn + nt * 16 + col;
                const float v = acc[mt][nt][e];
                const unsigned short h = f2b(v);
                Chi[(size_t)m * DIM + n] = h;
                if (Clo) Clo[(size_t)m * DIM + n] = f2b(v - b2f(h));
            }
}

// ---------------------------------------------------------------------------
// Scores: S[b] = (Q[b].K[b]^T) * 1/32, masked to -inf. fp32 output.
// ---------------------------------------------------------------------------
__global__ __launch_bounds__(256) void qk_mfma_kernel(
    const unsigned short* __restrict__ Qhi, const unsigned short* __restrict__ Qlo,
    const unsigned short* __restrict__ Khi, const unsigned short* __restrict__ Klo,
    const int* __restrict__ mask, float* __restrict__ Sc)
{
    __shared__ unsigned short Ah[128 * 32], Al[128 * 32];
    __shared__ unsigned short Bh[128 * 32], Bl[128 * 32];

    const int tid = threadIdx.x;
    const int w = tid >> 6, lane = tid & 63;
    const int wm = (w >> 1) * 64, wn = (w & 1) * 64;
    const int m0 = blockIdx.y * 128, n0 = blockIdx.x * 128;
    const int b = blockIdx.z;

    const unsigned short* __restrict__ Ahg = Qhi + (size_t)b * SEQ * DIM;
    const unsigned short* __restrict__ Alg = Qlo + (size_t)b * SEQ * DIM;
    const unsigned short* __restrict__ Bhg = Khi + (size_t)b * SEQ * DIM;
    const unsigned short* __restrict__ Blg = Klo + (size_t)b * SEQ * DIM;
    float* __restrict__ Sb = Sc + (size_t)b * SEQ * SEQ;

    f32x4 acc[4][4];
#pragma unroll
    for (int i = 0; i < 4; ++i)
#pragma unroll
        for (int j = 0; j < 4; ++j) acc[i][j] = (f32x4){0.f, 0.f, 0.f, 0.f};

    const int fr = lane & 15, quad = lane >> 4;
    const int qsw = quad ^ ((fr >> 2) & 3);

    for (int k0 = 0; k0 < DIM; k0 += 32) {
        stage_async(Ahg, DIM, m0, k0, Ah, tid);
        stage_async(Alg, DIM, m0, k0, Al, tid);
        stage_async(Bhg, DIM, n0, k0, Bh, tid);
        stage_async(Blg, DIM, n0, k0, Bl, tid);
        __syncthreads();

        bf16x8 ah[4], al[4];
#pragma unroll
        for (int mt = 0; mt < 4; ++mt) {
            ah[mt] = fragr(Ah, wm + mt * 16 + fr, qsw);
            al[mt] = fragr(Al, wm + mt * 16 + fr, qsw);
        }
#pragma unroll
        for (int nt = 0; nt < 4; ++nt) {
            const bf16x8 bh = fragr(Bh, wn + nt * 16 + fr, qsw);
            const bf16x8 bl = fragr(Bl, wn + nt * 16 + fr, qsw);
#pragma unroll
            for (int mt = 0; mt < 4; ++mt) {
                acc[mt][nt] = __builtin_amdgcn_mfma_f32_16x16x32_bf16(ah[mt], bh, acc[mt][nt], 0, 0, 0);
                acc[mt][nt] = __builtin_amdgcn_mfma_f32_16x16x32_bf16(ah[mt], bl, acc[mt][nt], 0, 0, 0);
                acc[mt][nt] = __builtin_amdgcn_mfma_f32_16x16x32_bf16(al[mt], bh, acc[mt][nt], 0, 0, 0);
            }
        }
        __syncthreads();
    }

    const int col = lane & 15, rq = lane >> 4;
#pragma unroll
    for (int mt = 0; mt < 4; ++mt)
#pragma unroll
        for (int nt = 0; nt < 4; ++nt)
#pragma unroll
            for (int e = 0; e < 4; ++e) {
                const int m = m0 + wm + mt * 16 + rq * 4 + e;
                const int n = n0 + wn + nt * 16 + col;
                const float v = acc[mt][nt][e] * 0.03125f;
                Sb[(size_t)m * SEQ + n] = mask[(size_t)m * SEQ + n] ? -INFINITY : v;
            }
}

// ---------------------------------------------------------------------------
// Row softmax on pre-masked, pre-scaled fp32 S; writes bf16 P in place
// (row r -> first 2048 ushorts of the row's 16 KB).
// ---------------------------------------------------------------------------
__global__ __launch_bounds__(256) void softmax_kernel(float* __restrict__ Sc)
{
    const int r = blockIdx.x;          // b*2048 + m
    float* __restrict__ row = Sc + (size_t)r * SEQ;

    const int tid  = threadIdx.x;
    const int lane = tid & 63;
    const int wid  = tid >> 6;

    float x[8];
    float mx = -INFINITY;
#pragma unroll
    for (int j = 0; j < 8; ++j) {
        x[j] = row[tid + j * 256];
        mx = fmaxf(mx, x[j]);
    }
    __shared__ float redm[4];
#pragma unroll
    for (int off = 32; off > 0; off >>= 1)
        mx = fmaxf(mx, __shfl_down(mx, off, 64));
    if (lane == 0) redm[wid] = mx;
    __syncthreads();
    mx = fmaxf(fmaxf(redm[0], redm[1]), fmaxf(redm[2], redm[3]));

    float sum = 0.f;
#pragma unroll
    for (int j = 0; j < 8; ++j) {
        const float e = __expf(x[j] - mx);
        x[j] = e;
        sum += e;
    }
    __shared__ float reds[4];
#pragma unroll
    for (int off = 32; off > 0; off >>= 1)
        sum += __shfl_down(sum, off, 64);
    if (lane == 0) reds[wid] = sum;
    __syncthreads();
    sum = (reds[0] + reds[1]) + (reds[2] + reds[3]);

    const float inv = 1.0f / sum;
    unsigned short* __restrict__ prow = (unsigned short*)row;
#pragma unroll
    for (int j = 0; j < 8; ++j)
        prow[tid + j * 256] = f2b(x[j] * inv);
}

// ---------------------------------------------------------------------------
// O[b] = P[b] @ V[b]: single bf16 MFMA, BK=64 (two staged sub-tiles/barrier).
// A = P rows (stride 4096 ushorts), B = Vt rows (n-major, k contiguous).
// ---------------------------------------------------------------------------
__global__ __launch_bounds__(256) void pv_mfma_kernel(
    const unsigned short* __restrict__ P, const unsigned short* __restrict__ Vt,
    float* __restrict__ O)
{
    __shared__ unsigned short As[2][128 * 32], Bs[2][128 * 32];

    const int tid = threadIdx.x;
    const int w = tid >> 6, lane = tid & 63;
    const int wm = (w >> 1) * 64, wn = (w & 1) * 64;
    const int m0 = blockIdx.y * 128, n0 = blockIdx.x * 128;
    const int b = blockIdx.z;

    const unsigned short* __restrict__ Ag = P + (size_t)b * SEQ * (2 * SEQ);
    const unsigned short* __restrict__ Bg = Vt + (size_t)b * DIM * SEQ;
    float* __restrict__ Ob = O + (size_t)b * SEQ * DIM;

    f32x4 acc[4][4];
#pragma unroll
    for (int i = 0; i < 4; ++i)
#pragma unroll
        for (int j = 0; j < 4; ++j) acc[i][j] = (f32x4){0.f, 0.f, 0.f, 0.f};

    const int fr = lane & 15, quad = lane >> 4;
    const int qsw = quad ^ ((fr >> 2) & 3);

    for (int k0 = 0; k0 < SEQ; k0 += 64) {
        stage_async(Ag, 2 * SEQ, m0, k0,      As[0], tid);
        stage_async(Ag, 2 * SEQ, m0, k0 + 32, As[1], tid);
        stage_async(Bg, SEQ,     n0, k0,      Bs[0], tid);
        stage_async(Bg, SEQ,     n0, k0 + 32, Bs[1], tid);
        __syncthreads();

#pragma unroll
        for (int s = 0; s < 2; ++s) {
            bf16x8 af[4];
#pragma unroll
            for (int mt = 0; mt < 4; ++mt)
                af[mt] = fragr(As[s], wm + mt * 16 + fr, qsw);
#pragma unroll
            for (int nt = 0; nt < 4; ++nt) {
                const bf16x8 bfg = fragr(Bs[s], wn + nt * 16 + fr, qsw);
#pragma unroll
                for (int mt = 0; mt < 4; ++mt)
                    acc[mt][nt] = __builtin_amdgcn_mfma_f32_16x16x32_bf16(af[mt], bfg, acc[mt][nt], 0, 0, 0);
            }
        }
        __syncthreads();
    }

    const int col = lane & 15, rq = lane >> 4;
#pragma unroll
    for (int mt = 0; mt < 4; ++mt)
#pragma unroll
        for (int nt = 0; nt < 4; ++nt)
#pragma unroll
            for (int e = 0; e < 4; ++e) {
                const int m = m0 + wm + mt * 16 + rq * 4 + e;
                const int n = n0 + wn + nt * 16 + col;
                Ob[(size_t)m * DIM + n] = acc[mt][nt][e];
            }
}

// ---------------------------------------------------------------------------
// Workspace layout (bytes), total = 167 772 160:
//   Qhi/Qlo/Khi/Klo/Vhi/Vt : 6 x 16 777 216  (bf16 [8192][1024] each)
//   S                      : 67 108 864      (fp32 [4][2048][2048])
// Transient, aliased INSIDE the S region (consumed before S is written):
//   Xhi/Xlo (33.5 MB) + WThi/WTlo (12.6 MB)
// P (bf16) written in place into S rows (row r at ushort offset r*4096).
// ---------------------------------------------------------------------------
extern "C" void kernel_launch(void* const* d_in, const int* in_sizes, int n_in,
                              void* d_out, int out_size, void* d_ws, size_t ws_size,
                              hipStream_t stream)
{
    const float* x    = (const float*)d_in[0];
    const int*   mask = (const int*)d_in[1];
    const float* wq   = (const float*)d_in[2];
    const float* wk   = (const float*)d_in[3];
    const float* wv   = (const float*)d_in[4];
    float* out = (float*)d_out;

    const size_t NQ = (size_t)BATCH * SEQ * DIM;     // 8 388 608
    unsigned short* Qhi = (unsigned short*)d_ws;
    unsigned short* Qlo = Qhi + NQ;
    unsigned short* Khi = Qlo + NQ;
    unsigned short* Klo = Khi + NQ;
    unsigned short* Vhi = Klo + NQ;
    unsigned short* Vt  = Vhi + NQ;
    float* Sc = (float*)(Vt + NQ);

    unsigned short* Xhi  = (unsigned short*)Sc;      // transient aliases
    unsigned short* Xlo  = Xhi + NQ;
    unsigned short* WThi = Xlo + NQ;
    unsigned short* WTlo = WThi + (size_t)3 * DIM * DIM;

    // 1. X -> hi/lo bf16
    convert_x_kernel<<<dim3(NQ / 4 / 256), 256, 0, stream>>>(x, Xhi, Xlo);
    // 2. W -> WT hi/lo bf16 (transposed to [n][k])
    convert_w_kernel<<<dim3(32, 32, 3), 256, 0, stream>>>(wq, wk, wv, WThi, WTlo);
    // 3. QKV projections; z = 0/1/2 -> Q/K/V (V: single term)
    proj_mfma_kernel<<<dim3(DIM / 128, BATCH * SEQ / 128, 3), 256, 0, stream>>>(
        Xhi, Xlo, WThi, WTlo, Qhi, Qlo, Khi, Klo, Vhi);
    // 4. V -> Vt (per batch [d][s])
    transpose_v_kernel<<<dim3(DIM / 32, SEQ / 32, BATCH), 256, 0, stream>>>(Vhi, Vt);
    // 5. S = masked, scaled Q.K^T (split-bf16 MFMA, fp32 scores)
    qk_mfma_kernel<<<dim3(SEQ / 128, SEQ / 128, BATCH), 256, 0, stream>>>(
        Qhi, Qlo, Khi, Klo, mask, Sc);
    // 6. softmax; writes bf16 P in place
    softmax_kernel<<<dim3(BATCH * SEQ), 256, 0, stream>>>(Sc);
    // 7. O = P @ V
    pv_mfma_kernel<<<dim3(DIM / 128, SEQ / 128, BATCH), 256, 0, stream>>>(
        (const unsigned short*)Sc, Vt, out);
}

// Round 4
// 394.944 us; speedup vs baseline: 3.9383x; 1.1007x over previous
//
#include <hip/hip_runtime.h>
#include <math.h>

static constexpr int BATCH = 4;
static constexpr int SEQ   = 2048;
static constexpr int DIM   = 1024;

typedef __attribute__((ext_vector_type(8))) short     bf16x8;  // MFMA A/B frag (4 VGPRs)
typedef __attribute__((ext_vector_type(4))) float     f32x4;   // MFMA C/D frag

// fp32 -> bf16 (RNE) and back, bit-exact helpers for hi/lo splitting
__device__ __forceinline__ unsigned short f2b(float v) {
    unsigned int u = __float_as_uint(v);
    u = u + 0x7fffu + ((u >> 16) & 1u);
    return (unsigned short)(u >> 16);
}
__device__ __forceinline__ float b2f(unsigned short h) {
    return __uint_as_float(((unsigned int)h) << 16);
}

// ---------------------------------------------------------------------------
// convert_x: fp32 -> (hi, lo) bf16, elementwise.
// ---------------------------------------------------------------------------
__global__ __launch_bounds__(256) void convert_x_kernel(
    const float* __restrict__ X, unsigned short* __restrict__ hi,
    unsigned short* __restrict__ lo)
{
    const int i = blockIdx.x * 256 + threadIdx.x;   // float4 index
    const float4 v = ((const float4*)X)[i];
    ushort4 h, l;
    h.x = f2b(v.x); l.x = f2b(v.x - b2f(h.x));
    h.y = f2b(v.y); l.y = f2b(v.y - b2f(h.y));
    h.z = f2b(v.z); l.z = f2b(v.z - b2f(h.z));
    h.w = f2b(v.w); l.w = f2b(v.w - b2f(h.w));
    ((ushort4*)hi)[i] = h;
    ((ushort4*)lo)[i] = l;
}

// ---------------------------------------------------------------------------
// convert_wqk: Wq (y=0) / Wk (y=1) fp32 -> hi/lo bf16, NO transpose.
// (M-gemm contracts over the output dim o, which is contiguous in W[i][o].)
// ---------------------------------------------------------------------------
__global__ __launch_bounds__(256) void convert_wqk_kernel(
    const float* __restrict__ Wq, const float* __restrict__ Wk,
    unsigned short* __restrict__ hi, unsigned short* __restrict__ lo)
{
    const int z = blockIdx.y;
    const float* __restrict__ W = z ? Wk : Wq;
    const int i = blockIdx.x * 256 + threadIdx.x;   // float4 index within matrix
    const int o = z * (DIM * DIM / 4) + i;
    const float4 v = ((const float4*)W)[i];
    ushort4 h, l;
    h.x = f2b(v.x); l.x = f2b(v.x - b2f(h.x));
    h.y = f2b(v.y); l.y = f2b(v.y - b2f(h.y));
    h.z = f2b(v.z); l.z = f2b(v.z - b2f(h.z));
    h.w = f2b(v.w); l.w = f2b(v.w - b2f(h.w));
    ((ushort4*)hi)[o] = h;
    ((ushort4*)lo)[o] = l;
}

// ---------------------------------------------------------------------------
// convert_wv: Wv[k][n] fp32 -> WvT[n][k] hi bf16 (V is single-term).
// ---------------------------------------------------------------------------
__global__ __launch_bounds__(256) void convert_wv_kernel(
    const float* __restrict__ W, unsigned short* __restrict__ WT)
{
    __shared__ float t[32][33];
    const int n0 = blockIdx.x * 32, k0 = blockIdx.y * 32;
    const int tx = threadIdx.x & 31, ty = threadIdx.x >> 5;  // ty: 0..7
#pragma unroll
    for (int i = 0; i < 4; ++i)
        t[ty + i * 8][tx] = W[(size_t)(k0 + ty + i * 8) * DIM + (n0 + tx)];
    __syncthreads();
#pragma unroll
    for (int i = 0; i < 4; ++i)
        WT[(size_t)(n0 + ty + i * 8) * DIM + (k0 + tx)] = f2b(t[tx][ty + i * 8]);
}

// ---------------------------------------------------------------------------
// Async staging of one 128-row x 32-elem bf16 tile via global_load_lds w=16.
// XOR-swizzled unpadded 64 B rows (see round 3); wave-uniform LDS dest.
// ---------------------------------------------------------------------------
__device__ __forceinline__ void stage_async(
    const unsigned short* __restrict__ g, int gstride, int row0, int k0,
    unsigned short* lds, int tid)
{
    const int w = tid >> 6, lane = tid & 63;
    const int c = (lane & 3) ^ ((lane >> 4) & 3);   // global chunk this lane fetches
#pragma unroll
    for (int h = 0; h < 2; ++h) {
        const int row = 32 * w + 16 * h + (lane >> 2);
        const unsigned short* src = g + (size_t)(row0 + row) * gstride + k0 + 8 * c;
        unsigned short* dst = lds + (32 * w + 16 * h) * 32;   // wave-uniform
        __builtin_amdgcn_global_load_lds(
            (const __attribute__((address_space(1))) void*)src,
            (__attribute__((address_space(3))) void*)dst, 16, 0, 0);
    }
}

__device__ __forceinline__ bf16x8 fragr(const unsigned short* lds, int row, int qsw)
{
    return *(const bf16x8*)(lds + row * 32 + qsw * 8);
}

// ---------------------------------------------------------------------------
// m_gemm: Mt = Wk . Wq^T  (so Mt[j][i] = sum_o Wq[i][o] Wk[j][o]), 3-term
// split bf16, 128x128 tile, K-split over z (4 chunks of 256). fp32 partials.
// ---------------------------------------------------------------------------
__global__ __launch_bounds__(256) void m_gemm_kernel(
    const unsigned short* __restrict__ Whi, const unsigned short* __restrict__ Wlo,
    float* __restrict__ Mtp)
{
    __shared__ unsigned short Ah[128 * 32], Al[128 * 32];
    __shared__ unsigned short Bh[128 * 32], Bl[128 * 32];

    const int tid = threadIdx.x;
    const int w = tid >> 6, lane = tid & 63;
    const int wm = (w >> 1) * 64, wn = (w & 1) * 64;
    const int m0 = blockIdx.y * 128, n0 = blockIdx.x * 128;
    const int z = blockIdx.z;                        // K chunk

    const unsigned short* __restrict__ Ahg = Whi + (size_t)DIM * DIM;  // Wk hi
    const unsigned short* __restrict__ Alg = Wlo + (size_t)DIM * DIM;  // Wk lo
    const unsigned short* __restrict__ Bhg = Whi;                      // Wq hi
    const unsigned short* __restrict__ Blg = Wlo;                      // Wq lo
    float* __restrict__ Cp = Mtp + (size_t)z * DIM * DIM;

    f32x4 acc[4][4];
#pragma unroll
    for (int i = 0; i < 4; ++i)
#pragma unroll
        for (int j = 0; j < 4; ++j) acc[i][j] = (f32x4){0.f, 0.f, 0.f, 0.f};

    const int fr = lane & 15, quad = lane >> 4;
    const int qsw = quad ^ ((fr >> 2) & 3);

    for (int k0 = z * 256; k0 < z * 256 + 256; k0 += 32) {
        stage_async(Ahg, DIM, m0, k0, Ah, tid);
        stage_async(Alg, DIM, m0, k0, Al, tid);
        stage_async(Bhg, DIM, n0, k0, Bh, tid);
        stage_async(Blg, DIM, n0, k0, Bl, tid);
        __syncthreads();

        bf16x8 ah[4], al[4];
#pragma unroll
        for (int mt = 0; mt < 4; ++mt) {
            ah[mt] = fragr(Ah, wm + mt * 16 + fr, qsw);
            al[mt] = fragr(Al, wm + mt * 16 + fr, qsw);
        }
#pragma unroll
        for (int nt = 0; nt < 4; ++nt) {
            const bf16x8 bh = fragr(Bh, wn + nt * 16 + fr, qsw);
            const bf16x8 bl = fragr(Bl, wn + nt * 16 + fr, qsw);
#pragma unroll
            for (int mt = 0; mt < 4; ++mt) {
                acc[mt][nt] = __builtin_amdgcn_mfma_f32_16x16x32_bf16(ah[mt], bh, acc[mt][nt], 0, 0, 0);
                acc[mt][nt] = __builtin_amdgcn_mfma_f32_16x16x32_bf16(ah[mt], bl, acc[mt][nt], 0, 0, 0);
                acc[mt][nt] = __builtin_amdgcn_mfma_f32_16x16x32_bf16(al[mt], bh, acc[mt][nt], 0, 0, 0);
            }
        }
        __syncthreads();
    }

    const int col = lane & 15, rq = lane >> 4;
#pragma unroll
    for (int mt = 0; mt < 4; ++mt)
#pragma unroll
        for (int nt = 0; nt < 4; ++nt)
#pragma unroll
            for (int e = 0; e < 4; ++e) {
                const int m = m0 + wm + mt * 16 + rq * 4 + e;
                const int n = n0 + wn + nt * 16 + col;
                Cp[(size_t)m * DIM + n] = acc[mt][nt][e];
            }
}

// ---------------------------------------------------------------------------
// m_reduce: sum 4 K-split partials, split to hi/lo bf16.
// ---------------------------------------------------------------------------
__global__ __launch_bounds__(256) void m_reduce_kernel(
    const float* __restrict__ Mtp, unsigned short* __restrict__ Mthi,
    unsigned short* __restrict__ Mtlo)
{
    const int i = blockIdx.x * 256 + threadIdx.x;   // float4 index
    const size_t q = (size_t)DIM * DIM / 4;
    const float4 a = ((const float4*)Mtp)[i];
    const float4 b = ((const float4*)Mtp)[i + q];
    const float4 c = ((const float4*)Mtp)[i + 2 * q];
    const float4 d = ((const float4*)Mtp)[i + 3 * q];
    const float4 v = make_float4(a.x + b.x + c.x + d.x, a.y + b.y + c.y + d.y,
                                 a.z + b.z + c.z + d.z, a.w + b.w + c.w + d.w);
    ushort4 h, l;
    h.x = f2b(v.x); l.x = f2b(v.x - b2f(h.x));
    h.y = f2b(v.y); l.y = f2b(v.y - b2f(h.y));
    h.z = f2b(v.z); l.z = f2b(v.z - b2f(h.z));
    h.w = f2b(v.w); l.w = f2b(v.w - b2f(h.w));
    ((ushort4*)Mthi)[i] = h;
    ((ushort4*)Mtlo)[i] = l;
}

// ---------------------------------------------------------------------------
// yv_gemm: z=0 -> Y = X @ Mt^T (3-term, hi/lo out, [8192][1024])
//          z=1 -> V = X @ WvT^T (1-term), written TRANSPOSED as Vt[b][d][s]
// ---------------------------------------------------------------------------
__global__ __launch_bounds__(256) void yv_gemm_kernel(
    const unsigned short* __restrict__ Xhi, const unsigned short* __restrict__ Xlo,
    const unsigned short* __restrict__ Mthi, const unsigned short* __restrict__ Mtlo,
    const unsigned short* __restrict__ WvT,
    unsigned short* __restrict__ Yhi, unsigned short* __restrict__ Ylo,
    unsigned short* __restrict__ Vt)
{
    __shared__ unsigned short Ah[128 * 32], Al[128 * 32];
    __shared__ unsigned short Bh[128 * 32], Bl[128 * 32];

    const int tid = threadIdx.x;
    const int w = tid >> 6, lane = tid & 63;
    const int wm = (w >> 1) * 64, wn = (w & 1) * 64;
    const int m0 = blockIdx.y * 128, n0 = blockIdx.x * 128;
    const int z = blockIdx.z;
    const bool full = (z == 0);

    const unsigned short* __restrict__ Bhg = full ? Mthi : WvT;
    const unsigned short* __restrict__ Blg = Mtlo;

    f32x4 acc[4][4];
#pragma unroll
    for (int i = 0; i < 4; ++i)
#pragma unroll
        for (int j = 0; j < 4; ++j) acc[i][j] = (f32x4){0.f, 0.f, 0.f, 0.f};

    const int fr = lane & 15, quad = lane >> 4;
    const int qsw = quad ^ ((fr >> 2) & 3);

    for (int k0 = 0; k0 < DIM; k0 += 32) {
        stage_async(Xhi, DIM, m0, k0, Ah, tid);
        stage_async(Bhg, DIM, n0, k0, Bh, tid);
        if (full) {
            stage_async(Xlo, DIM, m0, k0, Al, tid);
            stage_async(Blg, DIM, n0, k0, Bl, tid);
        }
        __syncthreads();

        bf16x8 ah[4], al[4];
#pragma unroll
        for (int mt = 0; mt < 4; ++mt)
            ah[mt] = fragr(Ah, wm + mt * 16 + fr, qsw);
        if (full) {
#pragma unroll
            for (int mt = 0; mt < 4; ++mt)
                al[mt] = fragr(Al, wm + mt * 16 + fr, qsw);
        }
#pragma unroll
        for (int nt = 0; nt < 4; ++nt) {
            const bf16x8 bh = fragr(Bh, wn + nt * 16 + fr, qsw);
#pragma unroll
            for (int mt = 0; mt < 4; ++mt)
                acc[mt][nt] = __builtin_amdgcn_mfma_f32_16x16x32_bf16(ah[mt], bh, acc[mt][nt], 0, 0, 0);
            if (full) {
                const bf16x8 bl = fragr(Bl, wn + nt * 16 + fr, qsw);
#pragma unroll
                for (int mt = 0; mt < 4; ++mt) {
                    acc[mt][nt] = __builtin_amdgcn_mfma_f32_16x16x32_bf16(ah[mt], bl, acc[mt][nt], 0, 0, 0);
                    acc[mt][nt] = __builtin_amdgcn_mfma_f32_16x16x32_bf16(al[mt], bh, acc[mt][nt], 0, 0, 0);
                }
            }
        }
        __syncthreads();
    }

    const int col = lane & 15, rq = lane >> 4;
    if (full) {
#pragma unroll
        for (int mt = 0; mt < 4; ++mt)
#pragma unroll
            for (int nt = 0; nt < 4; ++nt)
#pragma unroll
                for (int e = 0; e < 4; ++e) {
                    const int m = m0 + wm + mt * 16 + rq * 4 + e;
                    const int n = n0 + wn + nt * 16 + col;
                    const float v = acc[mt][nt][e];
                    const unsigned short h = f2b(v);
                    Yhi[(size_t)m * DIM + n] = h;
                    Ylo[(size_t)m * DIM + n] = f2b(v - b2f(h));
                }
    } else {
        // V: write transposed, Vt[b][n][s], 4 consecutive s per ushort4
#pragma unroll
        for (int mt = 0; mt < 4; ++mt)
#pragma unroll
            for (int nt = 0; nt < 4; ++nt) {
                const int m = m0 + wm + mt * 16 + rq * 4;      // 4-aligned
                const int bb = m >> 11, s = m & (SEQ - 1);
                const int n = n0 + wn + nt * 16 + col;
                ushort4 pk;
                pk.x = f2b(acc[mt][nt][0]);
                pk.y = f2b(acc[mt][nt][1]);
                pk.z = f2b(acc[mt][nt][2]);
                pk.w = f2b(acc[mt][nt][3]);
                *(ushort4*)(Vt + (size_t)bb * DIM * SEQ + (size_t)n * SEQ + s) = pk;
            }
    }
}

// ---------------------------------------------------------------------------
// s_gemm: S[b] = (Y[b] . X[b]^T) * 1/32, masked to -inf. fp32 output.
// 3-term split bf16; A = Y hi/lo, B = X hi/lo (per batch).
// ---------------------------------------------------------------------------
__global__ __launch_bounds__(256) void s_gemm_kernel(
    const unsigned short* __restrict__ Yhi, const unsigned short* __restrict__ Ylo,
    const unsigned short* __restrict__ Xhi, const unsigned short* __restrict__ Xlo,
    const int* __restrict__ mask, float* __restrict__ Sc)
{
    __shared__ unsigned short Ah[128 * 32], Al[128 * 32];
    __shared__ unsigned short Bh[128 * 32], Bl[128 * 32];

    const int tid = threadIdx.x;
    const int w = tid >> 6, lane = tid & 63;
    const int wm = (w >> 1) * 64, wn = (w & 1) * 64;
    const int m0 = blockIdx.y * 128, n0 = blockIdx.x * 128;
    const int b = blockIdx.z;

    const unsigned short* __restrict__ Ahg = Yhi + (size_t)b * SEQ * DIM;
    const unsigned short* __restrict__ Alg = Ylo + (size_t)b * SEQ * DIM;
    const unsigned short* __restrict__ Bhg = Xhi + (size_t)b * SEQ * DIM;
    const unsigned short* __restrict__ Blg = Xlo + (size_t)b * SEQ * DIM;
    float* __restrict__ Sb = Sc + (size_t)b * SEQ * SEQ;

    f32x4 acc[4][4];
#pragma unroll
    for (int i = 0; i < 4; ++i)
#pragma unroll
        for (int j = 0; j < 4; ++j) acc[i][j] = (f32x4){0.f, 0.f, 0.f, 0.f};

    const int fr = lane & 15, quad = lane >> 4;
    const int qsw = quad ^ ((fr >> 2) & 3);

    for (int k0 = 0; k0 < DIM; k0 += 32) {
        stage_async(Ahg, DIM, m0, k0, Ah, tid);
        stage_async(Alg, DIM, m0, k0, Al, tid);
        stage_async(Bhg, DIM, n0, k0, Bh, tid);
        stage_async(Blg, DIM, n0, k0, Bl, tid);
        __syncthreads();

        bf16x8 ah[4], al[4];
#pragma unroll
        for (int mt = 0; mt < 4; ++mt) {
            ah[mt] = fragr(Ah, wm + mt * 16 + fr, qsw);
            al[mt] = fragr(Al, wm + mt * 16 + fr, qsw);
        }
#pragma unroll
        for (int nt = 0; nt < 4; ++nt) {
            const bf16x8 bh = fragr(Bh, wn + nt * 16 + fr, qsw);
            const bf16x8 bl = fragr(Bl, wn + nt * 16 + fr, qsw);
#pragma unroll
            for (int mt = 0; mt < 4; ++mt) {
                acc[mt][nt] = __builtin_amdgcn_mfma_f32_16x16x32_bf16(ah[mt], bh, acc[mt][nt], 0, 0, 0);
                acc[mt][nt] = __builtin_amdgcn_mfma_f32_16x16x32_bf16(ah[mt], bl, acc[mt][nt], 0, 0, 0);
                acc[mt][nt] = __builtin_amdgcn_mfma_f32_16x16x32_bf16(al[mt], bh, acc[mt][nt], 0, 0, 0);
            }
        }
        __syncthreads();
    }

    const int col = lane & 15, rq = lane >> 4;
#pragma unroll
    for (int mt = 0; mt < 4; ++mt)
#pragma unroll
        for (int nt = 0; nt < 4; ++nt)
#pragma unroll
            for (int e = 0; e < 4; ++e) {
                const int m = m0 + wm + mt * 16 + rq * 4 + e;
                const int n = n0 + wn + nt * 16 + col;
                const float v = acc[mt][nt][e] * 0.03125f;
                Sb[(size_t)m * SEQ + n] = mask[(size_t)m * SEQ + n] ? -INFINITY : v;
            }
}

// ---------------------------------------------------------------------------
// Row softmax on pre-masked, pre-scaled fp32 S; writes bf16 P in place
// (row r -> first 2048 ushorts of the row's 16 KB).
// ---------------------------------------------------------------------------
__global__ __launch_bounds__(256) void softmax_kernel(float* __restrict__ Sc)
{
    const int r = blockIdx.x;          // b*2048 + m
    float* __restrict__ row = Sc + (size_t)r * SEQ;

    const int tid  = threadIdx.x;
    const int lane = tid & 63;
    const int wid  = tid >> 6;

    float x[8];
    float mx = -INFINITY;
#pragma unroll
    for (int j = 0; j < 8; ++j) {
        x[j] = row[tid + j * 256];
        mx = fmaxf(mx, x[j]);
    }
    __shared__ float redm[4];
#pragma unroll
    for (int off = 32; off > 0; off >>= 1)
        mx = fmaxf(mx, __shfl_down(mx, off, 64));
    if (lane == 0) redm[wid] = mx;
    __syncthreads();
    mx = fmaxf(fmaxf(redm[0], redm[1]), fmaxf(redm[2], redm[3]));

    float sum = 0.f;
#pragma unroll
    for (int j = 0; j < 8; ++j) {
        const float e = __expf(x[j] - mx);
        x[j] = e;
        sum += e;
    }
    __shared__ float reds[4];
#pragma unroll
    for (int off = 32; off > 0; off >>= 1)
        sum += __shfl_down(sum, off, 64);
    if (lane == 0) reds[wid] = sum;
    __syncthreads();
    sum = (reds[0] + reds[1]) + (reds[2] + reds[3]);

    const float inv = 1.0f / sum;
    unsigned short* __restrict__ prow = (unsigned short*)row;
#pragma unroll
    for (int j = 0; j < 8; ++j)
        prow[tid + j * 256] = f2b(x[j] * inv);
}

// ---------------------------------------------------------------------------
// O[b] = P[b] @ V[b]: single bf16 MFMA, BK=64 (two staged sub-tiles/barrier).
// A = P rows (stride 4096 ushorts), B = Vt rows (n-major, k contiguous).
// ---------------------------------------------------------------------------
__global__ __launch_bounds__(256) void pv_mfma_kernel(
    const unsigned short* __restrict__ P, const unsigned short* __restrict__ Vt,
    float* __restrict__ O)
{
    __shared__ unsigned short As[2][128 * 32], Bs[2][128 * 32];

    const int tid = threadIdx.x;
    const int w = tid >> 6, lane = tid & 63;
    const int wm = (w >> 1) * 64, wn = (w & 1) * 64;
    const int m0 = blockIdx.y * 128, n0 = blockIdx.x * 128;
    const int b = blockIdx.z;

    const unsigned short* __restrict__ Ag = P + (size_t)b * SEQ * (2 * SEQ);
    const unsigned short* __restrict__ Bg = Vt + (size_t)b * DIM * SEQ;
    float* __restrict__ Ob = O + (size_t)b * SEQ * DIM;

    f32x4 acc[4][4];
#pragma unroll
    for (int i = 0; i < 4; ++i)
#pragma unroll
        for (int j = 0; j < 4; ++j) acc[i][j] = (f32x4){0.f, 0.f, 0.f, 0.f};

    const int fr = lane & 15, quad = lane >> 4;
    const int qsw = quad ^ ((fr >> 2) & 3);

    for (int k0 = 0; k0 < SEQ; k0 += 64) {
        stage_async(Ag, 2 * SEQ, m0, k0,      As[0], tid);
        stage_async(Ag, 2 * SEQ, m0, k0 + 32, As[1], tid);
        stage_async(Bg, SEQ,     n0, k0,      Bs[0], tid);
        stage_async(Bg, SEQ,     n0, k0 + 32, Bs[1], tid);
        __syncthreads();

#pragma unroll
        for (int s = 0; s < 2; ++s) {
            bf16x8 af[4];
#pragma unroll
            for (int mt = 0; mt < 4; ++mt)
                af[mt] = fragr(As[s], wm + mt * 16 + fr, qsw);
#pragma unroll
            for (int nt = 0; nt < 4; ++nt) {
                const bf16x8 bfg = fragr(Bs[s], wn + nt * 16 + fr, qsw);
#pragma unroll
                for (int mt = 0; mt < 4; ++mt)
                    acc[mt][nt] = __builtin_amdgcn_mfma_f32_16x16x32_bf16(af[mt], bfg, acc[mt][nt], 0, 0, 0);
            }
        }
        __syncthreads();
    }

    const int col = lane & 15, rq = lane >> 4;
#pragma unroll
    for (int mt = 0; mt < 4; ++mt)
#pragma unroll
        for (int nt = 0; nt < 4; ++nt)
#pragma unroll
            for (int e = 0; e < 4; ++e) {
                const int m = m0 + wm + mt * 16 + rq * 4 + e;
                const int n = n0 + wn + nt * 16 + col;
                Ob[(size_t)m * DIM + n] = acc[mt][nt][e];
            }
}

// ---------------------------------------------------------------------------
// Workspace layout (bytes), ws = 167 772 160:
//   Xhi/Xlo/Yhi/Ylo/Vt : 5 x 16 777 216   (bf16 [8192][1024]-sized each)
//   Mthi/Mtlo          : 2 x  2 097 152   (bf16 [1024][1024])
//   Sc                 : 67 108 864       (fp32 [4][2048][2048])  -> 155.2 MB
// Transients aliased INSIDE Sc (consumed before s_gemm writes Sc):
//   Whi/Wlo (2x4.2 MB) + WvT (2.1 MB) + Mtp (4x4.2 MB fp32) = 27.3 MB
// P (bf16) written in place into Sc rows (row r at ushort offset r*4096).
// ---------------------------------------------------------------------------
extern "C" void kernel_launch(void* const* d_in, const int* in_sizes, int n_in,
                              void* d_out, int out_size, void* d_ws, size_t ws_size,
                              hipStream_t stream)
{
    const float* x    = (const float*)d_in[0];
    const int*   mask = (const int*)d_in[1];
    const float* wq   = (const float*)d_in[2];
    const float* wk   = (const float*)d_in[3];
    const float* wv   = (const float*)d_in[4];
    float* out = (float*)d_out;

    const size_t NQ = (size_t)BATCH * SEQ * DIM;     // 8 388 608
    const size_t NM = (size_t)DIM * DIM;             // 1 048 576
    unsigned short* Xhi  = (unsigned short*)d_ws;
    unsigned short* Xlo  = Xhi + NQ;
    unsigned short* Yhi  = Xlo + NQ;
    unsigned short* Ylo  = Yhi + NQ;
    unsigned short* Vt   = Ylo + NQ;
    unsigned short* Mthi = Vt + NQ;
    unsigned short* Mtlo = Mthi + NM;
    float* Sc = (float*)(Mtlo + NM);

    unsigned short* Whi = (unsigned short*)Sc;       // transient aliases
    unsigned short* Wlo = Whi + 2 * NM;
    unsigned short* WvT = Wlo + 2 * NM;
    float* Mtp = (float*)(WvT + NM);

    // 1. X -> hi/lo bf16
    convert_x_kernel<<<dim3(NQ / 4 / 256), 256, 0, stream>>>(x, Xhi, Xlo);
    // 2. Wq/Wk -> hi/lo bf16 (no transpose); Wv -> WvT hi bf16
    convert_wqk_kernel<<<dim3(NM / 4 / 256, 2), 256, 0, stream>>>(wq, wk, Whi, Wlo);
    convert_wv_kernel<<<dim3(32, 32), 256, 0, stream>>>(wv, WvT);
    // 3. Mt = Wk.Wq^T (K-split x4, fp32 partials), then reduce + hi/lo split
    m_gemm_kernel<<<dim3(8, 8, 4), 256, 0, stream>>>(Whi, Wlo, Mtp);
    m_reduce_kernel<<<dim3(NM / 4 / 256), 256, 0, stream>>>(Mtp, Mthi, Mtlo);
    // 4. z=0: Y = X.Mt^T (hi/lo out); z=1: V = X.WvT^T written as Vt[b][d][s]
    yv_gemm_kernel<<<dim3(DIM / 128, (BATCH * SEQ) / 128, 2), 256, 0, stream>>>(
        Xhi, Xlo, Mthi, Mtlo, WvT, Yhi, Ylo, Vt);
    // 5. S = masked, scaled Y.X^T per batch (fp32 scores)
    s_gemm_kernel<<<dim3(SEQ / 128, SEQ / 128, BATCH), 256, 0, stream>>>(
        Yhi, Ylo, Xhi, Xlo, mask, Sc);
    // 6. softmax; writes bf16 P in place
    softmax_kernel<<<dim3(BATCH * SEQ), 256, 0, stream>>>(Sc);
    // 7. O = P @ V
    pv_mfma_kernel<<<dim3(DIM / 128, SEQ / 128, BATCH), 256, 0, stream>>>(
        (const unsigned short*)Sc, Vt, out);
}